// Round 1
// baseline (1551.050 us; speedup 1.0000x reference)
//
#include <hip/hip_runtime.h>

// GraphSAGE link predictor, f32 baseline.
// Pipeline:
//  CSR build (deg hist -> scan -> bucket) ->
//  aggX = segsum(x[src])              (gather, wave/node)
//  h1 = (aggX/cnt)@Wl1 + bl1 + x@Wr1  (lane/node, scalar-W)
//  g  = h1@Wl2                         (lane/node)
//  aggG = segsum(g[src])               (gather)       [linearity: mean(h1)@Wl2 = segsum(g)/cnt]
//  h2 = aggG/cnt + bl2 + h1@Wr2        (lane/node)
//  out[e] = relu((h2[s]*h2[d])@W1+b1)@W2 + b2   (lane/edge, scalar-W, fused)

// ---------------- prep: weight transposes ----------------
__global__ void k_prep(const float* __restrict__ Wl1, const float* __restrict__ Wr1,
                       const float* __restrict__ W1,
                       const float* __restrict__ Wl2, const float* __restrict__ Wr2,
                       float* __restrict__ WlT1, float* __restrict__ WrT1,
                       float* __restrict__ W1t,
                       float* __restrict__ Wl2T, float* __restrict__ Wr2T) {
  int t = blockIdx.x * blockDim.x + threadIdx.x;
  if (t >= 64 * 128) return;
  {
    int i = t / 128, j = t % 128;   // [64][128] -> [128][64]
    WlT1[j * 64 + i] = Wl1[t];
    WrT1[j * 64 + i] = Wr1[t];
    W1t [j * 64 + i] = W1[t];
  }
  {
    int i = t / 64, j = t % 64;     // [128][64] -> [64][128]
    Wl2T[j * 128 + i] = Wl2[t];
    Wr2T[j * 128 + i] = Wr2[t];
  }
}

// ---------------- CSR build ----------------
__global__ void k_hist(const int* __restrict__ dst, int* __restrict__ deg, int E) {
  int e = blockIdx.x * blockDim.x + threadIdx.x;
  if (e < E) atomicAdd(&deg[dst[e]], 1);
}

// per-block exclusive scan; ex -> cursor (temp), block totals -> bsum
__global__ void k_scan1(const int* __restrict__ deg, int* __restrict__ ex,
                        int* __restrict__ bsum, int N) {
  __shared__ int sm[256];
  int t = threadIdx.x, i = blockIdx.x * 256 + t;
  int v = (i < N) ? deg[i] : 0;
  sm[t] = v;
  __syncthreads();
  for (int s = 1; s < 256; s <<= 1) {
    int a = (t >= s) ? sm[t - s] : 0;
    __syncthreads();
    sm[t] += a;
    __syncthreads();
  }
  if (i < N) ex[i] = sm[t] - v;           // exclusive within block
  if (t == 255) bsum[blockIdx.x] = sm[255];
}

__global__ void k_scan2(int* __restrict__ bsum, int nb) {
  __shared__ int sm[1024];
  int t = threadIdx.x;
  int v = (t < nb) ? bsum[t] : 0;
  sm[t] = v;
  __syncthreads();
  for (int s = 1; s < 1024; s <<= 1) {
    int a = (t >= s) ? sm[t - s] : 0;
    __syncthreads();
    sm[t] += a;
    __syncthreads();
  }
  if (t < nb) bsum[t] = sm[t] - v;        // exclusive block offsets
}

__global__ void k_scan3(const int* __restrict__ bsum, int* __restrict__ row,
                        int* __restrict__ cursor, int N, int E) {
  int i = blockIdx.x * blockDim.x + threadIdx.x;
  if (i < N) {
    int v = cursor[i] + bsum[i >> 8];
    row[i] = v;
    cursor[i] = v;
  }
  if (i == 0) row[N] = E;
}

__global__ void k_bucket(const int* __restrict__ src, const int* __restrict__ dst,
                         int* __restrict__ cursor, int* __restrict__ srcs, int E) {
  int e = blockIdx.x * blockDim.x + threadIdx.x;
  if (e < E) {
    int pos = atomicAdd(&cursor[dst[e]], 1);
    srcs[pos] = src[e];
  }
}

// ---------------- aggregation: one wave per node, 64-dim features ----------------
__global__ void k_gather64(const float* __restrict__ feat, const int* __restrict__ row,
                           const int* __restrict__ srcs, float* __restrict__ agg, int N) {
  int gid = blockIdx.x * blockDim.x + threadIdx.x;
  int wid = gid >> 6, lane = gid & 63;
  if (wid >= N) return;
  int beg = row[wid], end = row[wid + 1];
  float acc = 0.f;
  for (int k = beg; k < end; k++) {
    int s = srcs[k];
    acc += feat[(size_t)s * 64 + lane];
  }
  agg[(size_t)wid * 64 + lane] = acc;
}

// ---------------- h1 = mean@Wl1 + bl1 + x@Wr1 : one node per lane ----------------
__global__ __launch_bounds__(256) void k_h1(
    const float* __restrict__ x, const float* __restrict__ aggX,
    const int* __restrict__ deg,
    const float* __restrict__ WlT1, const float* __restrict__ WrT1,
    const float* __restrict__ bl1, float* __restrict__ h1, int N) {
  int node = blockIdx.x * blockDim.x + threadIdx.x;
  if (node >= N) return;
  float xr[64], mr[64];
  const float4* xv = (const float4*)(x + (size_t)node * 64);
  const float4* av = (const float4*)(aggX + (size_t)node * 64);
  float inv = 1.0f / fmaxf((float)deg[node], 1.0f);
#pragma unroll
  for (int i = 0; i < 16; i++) {
    float4 a = xv[i];
    xr[4 * i] = a.x; xr[4 * i + 1] = a.y; xr[4 * i + 2] = a.z; xr[4 * i + 3] = a.w;
    float4 m = av[i];
    mr[4 * i] = m.x * inv; mr[4 * i + 1] = m.y * inv;
    mr[4 * i + 2] = m.z * inv; mr[4 * i + 3] = m.w * inv;
  }
  float4* outv = (float4*)(h1 + (size_t)node * 128);
  for (int j4 = 0; j4 < 32; j4++) {
    float r0, r1, r2, r3;
#pragma unroll
    for (int q = 0; q < 4; q++) {
      int j = j4 * 4 + q;
      float a0 = 0.f, a1 = 0.f;
#pragma unroll
      for (int i = 0; i < 64; i += 2) {
        a0 += mr[i] * WlT1[j * 64 + i] + xr[i] * WrT1[j * 64 + i];
        a1 += mr[i + 1] * WlT1[j * 64 + i + 1] + xr[i + 1] * WrT1[j * 64 + i + 1];
      }
      float r = a0 + a1 + bl1[j];
      if (q == 0) r0 = r; else if (q == 1) r1 = r; else if (q == 2) r2 = r; else r3 = r;
    }
    outv[j4] = make_float4(r0, r1, r2, r3);
  }
}

// ---------------- g = h1@Wl2 : one node per lane ----------------
__global__ __launch_bounds__(256) void k_g(
    const float* __restrict__ h1, const float* __restrict__ Wl2T,
    float* __restrict__ g, int N) {
  int node = blockIdx.x * blockDim.x + threadIdx.x;
  if (node >= N) return;
  float hr[128];
  const float4* hv = (const float4*)(h1 + (size_t)node * 128);
#pragma unroll
  for (int i = 0; i < 32; i++) {
    float4 a = hv[i];
    hr[4 * i] = a.x; hr[4 * i + 1] = a.y; hr[4 * i + 2] = a.z; hr[4 * i + 3] = a.w;
  }
  float4* outv = (float4*)(g + (size_t)node * 64);
  for (int j4 = 0; j4 < 16; j4++) {
    float r0, r1, r2, r3;
#pragma unroll
    for (int q = 0; q < 4; q++) {
      int j = j4 * 4 + q;
      float a0 = 0.f, a1 = 0.f;
#pragma unroll
      for (int i = 0; i < 128; i += 2) {
        a0 += hr[i] * Wl2T[j * 128 + i];
        a1 += hr[i + 1] * Wl2T[j * 128 + i + 1];
      }
      float r = a0 + a1;
      if (q == 0) r0 = r; else if (q == 1) r1 = r; else if (q == 2) r2 = r; else r3 = r;
    }
    outv[j4] = make_float4(r0, r1, r2, r3);
  }
}

// ---------------- h2 = aggG/cnt + bl2 + h1@Wr2 : one node per lane ----------------
__global__ __launch_bounds__(256) void k_h2(
    const float* __restrict__ h1, const float* __restrict__ aggG,
    const int* __restrict__ deg, const float* __restrict__ Wr2T,
    const float* __restrict__ bl2, float* __restrict__ h2, int N) {
  int node = blockIdx.x * blockDim.x + threadIdx.x;
  if (node >= N) return;
  float hr[128], ar[64];
  const float4* hv = (const float4*)(h1 + (size_t)node * 128);
  const float4* av = (const float4*)(aggG + (size_t)node * 64);
  float inv = 1.0f / fmaxf((float)deg[node], 1.0f);
#pragma unroll
  for (int i = 0; i < 32; i++) {
    float4 a = hv[i];
    hr[4 * i] = a.x; hr[4 * i + 1] = a.y; hr[4 * i + 2] = a.z; hr[4 * i + 3] = a.w;
  }
#pragma unroll
  for (int i = 0; i < 16; i++) {
    float4 a = av[i];
    ar[4 * i] = a.x * inv; ar[4 * i + 1] = a.y * inv;
    ar[4 * i + 2] = a.z * inv; ar[4 * i + 3] = a.w * inv;
  }
  float4* outv = (float4*)(h2 + (size_t)node * 64);
  for (int j4 = 0; j4 < 16; j4++) {
    float r0, r1, r2, r3;
#pragma unroll
    for (int q = 0; q < 4; q++) {
      int j = j4 * 4 + q;
      float a0 = 0.f, a1 = 0.f;
#pragma unroll
      for (int i = 0; i < 128; i += 2) {
        a0 += hr[i] * Wr2T[j * 128 + i];
        a1 += hr[i + 1] * Wr2T[j * 128 + i + 1];
      }
      float r = a0 + a1 + ar[j] + bl2[j];
      if (q == 0) r0 = r; else if (q == 1) r1 = r; else if (q == 2) r2 = r; else r3 = r;
    }
    outv[j4] = make_float4(r0, r1, r2, r3);
  }
}

// ---------------- edge MLP: out = relu((h2[s]*h2[d])@W1+b1)@W2 + b2, one edge/lane --
__global__ __launch_bounds__(256) void k_edge(
    const float* __restrict__ h2, const int* __restrict__ src,
    const int* __restrict__ dst, const float* __restrict__ W1t,
    const float* __restrict__ W2, const float* __restrict__ b1,
    const float* __restrict__ b2, float* __restrict__ out, int E) {
  int e = blockIdx.x * blockDim.x + threadIdx.x;
  if (e >= E) return;
  int s = src[e], d = dst[e];
  float ev[64];
  const float4* hs = (const float4*)(h2 + (size_t)s * 64);
  const float4* hd = (const float4*)(h2 + (size_t)d * 64);
#pragma unroll
  for (int i = 0; i < 16; i++) {
    float4 a = hs[i], b = hd[i];
    ev[4 * i] = a.x * b.x; ev[4 * i + 1] = a.y * b.y;
    ev[4 * i + 2] = a.z * b.z; ev[4 * i + 3] = a.w * b.w;
  }
  float o = b2[0];
  for (int k = 0; k < 128; k++) {
    float a0 = 0.f, a1 = 0.f, a2 = 0.f, a3 = 0.f;
#pragma unroll
    for (int i = 0; i < 64; i += 4) {
      a0 += ev[i] * W1t[k * 64 + i];
      a1 += ev[i + 1] * W1t[k * 64 + i + 1];
      a2 += ev[i + 2] * W1t[k * 64 + i + 2];
      a3 += ev[i + 3] * W1t[k * 64 + i + 3];
    }
    float t = a0 + a1 + a2 + a3 + b1[k];
    o += fmaxf(t, 0.f) * W2[k];
  }
  out[e] = o;
}

// ---------------- launch ----------------
extern "C" void kernel_launch(void* const* d_in, const int* in_sizes, int n_in,
                              void* d_out, int out_size, void* d_ws, size_t ws_size,
                              hipStream_t stream) {
  const float* x   = (const float*)d_in[0];
  const int*   ei  = (const int*)d_in[1];
  const float* Wl1 = (const float*)d_in[2];
  const float* bl1 = (const float*)d_in[3];
  const float* Wr1 = (const float*)d_in[4];
  const float* Wl2 = (const float*)d_in[5];
  const float* bl2 = (const float*)d_in[6];
  const float* Wr2 = (const float*)d_in[7];
  const float* W1  = (const float*)d_in[8];
  const float* b1  = (const float*)d_in[9];
  const float* W2  = (const float*)d_in[10];
  const float* b2  = (const float*)d_in[11];
  const int N = in_sizes[0] / 64;
  const int E = in_sizes[1] / 2;
  const int* src = ei;
  const int* dstp = ei + E;

  char* w = (char*)d_ws;
  size_t off = 0;
  auto alloc = [&](size_t bytes) -> void* {
    void* p = w + off;
    off = (off + bytes + 255) & ~(size_t)255;
    return p;
  };
  int*   deg    = (int*)alloc((size_t)N * 4);
  int*   row    = (int*)alloc((size_t)(N + 1) * 4);
  int*   cursor = (int*)alloc((size_t)N * 4);
  int*   bsum   = (int*)alloc(1024 * 4);
  float* WlT1   = (float*)alloc(8192 * 4);
  float* WrT1   = (float*)alloc(8192 * 4);
  float* W1t    = (float*)alloc(8192 * 4);
  float* Wl2T   = (float*)alloc(8192 * 4);
  float* Wr2T   = (float*)alloc(8192 * 4);
  int*   srcs   = (int*)alloc((size_t)E * 4);
  float* aggX   = (float*)alloc((size_t)N * 64 * 4);   // reused as aggG
  float* h1     = (float*)alloc((size_t)N * 128 * 4);
  float* gbuf   = (float*)alloc((size_t)N * 64 * 4);   // g, reused as h2

  hipMemsetAsync(deg, 0, (size_t)N * 4, stream);
  k_prep<<<32, 256, 0, stream>>>(Wl1, Wr1, W1, Wl2, Wr2, WlT1, WrT1, W1t, Wl2T, Wr2T);
  k_hist<<<(E + 255) / 256, 256, 0, stream>>>(dstp, deg, E);
  int nb = (N + 255) / 256;
  k_scan1<<<nb, 256, 0, stream>>>(deg, cursor, bsum, N);
  k_scan2<<<1, 1024, 0, stream>>>(bsum, nb);
  k_scan3<<<nb, 256, 0, stream>>>(bsum, row, cursor, N, E);
  k_bucket<<<(E + 255) / 256, 256, 0, stream>>>(src, dstp, cursor, srcs, E);

  k_gather64<<<(N * 64 + 255) / 256, 256, 0, stream>>>(x, row, srcs, aggX, N);
  k_h1<<<(N + 255) / 256, 256, 0, stream>>>(x, aggX, deg, WlT1, WrT1, bl1, h1, N);
  k_g<<<(N + 255) / 256, 256, 0, stream>>>(h1, Wl2T, gbuf, N);
  k_gather64<<<(N * 64 + 255) / 256, 256, 0, stream>>>(gbuf, row, srcs, aggX, N);
  k_h2<<<(N + 255) / 256, 256, 0, stream>>>(h1, aggX, deg, Wr2T, bl2, gbuf, N);
  k_edge<<<(E + 255) / 256, 256, 0, stream>>>(gbuf, src, dstp, W1t, W2, b1, b2,
                                              (float*)d_out, E);
}

// Round 2
// 735.720 us; speedup vs baseline: 2.1082x; 2.1082x over previous
//
#include <hip/hip_runtime.h>

// GraphSAGE link predictor, f32, tiled node GEMMs.
// Pipeline:
//  CSR build (deg hist -> scan -> bucket)
//  aggX = segsum(x[src])                       (gather, wave/node)
//  h1 = (aggX@Wl1)*inv + x@Wr1 + bl1           (tiled GEMM, MODE 0)
//  g  = h1@Wl2                                 (tiled GEMM, MODE 1)
//  aggG = segsum(g[src])                       (gather)
//  h2 = h1@Wr2 + aggG*inv + bl2                (tiled GEMM, MODE 2)
//  out[e] = relu((h2[s]*h2[d])@W1+b1)@W2 + b2  (lane/edge)

// ---------------- prep: W1 transpose for edge kernel ----------------
__global__ void k_prep(const float* __restrict__ W1, float* __restrict__ W1t) {
  int t = blockIdx.x * blockDim.x + threadIdx.x;
  if (t >= 64 * 128) return;
  int i = t / 128, j = t % 128;   // [64][128] -> [128][64]
  W1t[j * 64 + i] = W1[t];
}

// ---------------- CSR build ----------------
__global__ void k_hist(const int* __restrict__ dst, int* __restrict__ deg, int E) {
  int e = blockIdx.x * blockDim.x + threadIdx.x;
  if (e < E) atomicAdd(&deg[dst[e]], 1);
}

__global__ void k_scan1(const int* __restrict__ deg, int* __restrict__ ex,
                        int* __restrict__ bsum, int N) {
  __shared__ int sm[256];
  int t = threadIdx.x, i = blockIdx.x * 256 + t;
  int v = (i < N) ? deg[i] : 0;
  sm[t] = v;
  __syncthreads();
  for (int s = 1; s < 256; s <<= 1) {
    int a = (t >= s) ? sm[t - s] : 0;
    __syncthreads();
    sm[t] += a;
    __syncthreads();
  }
  if (i < N) ex[i] = sm[t] - v;
  if (t == 255) bsum[blockIdx.x] = sm[255];
}

__global__ void k_scan2(int* __restrict__ bsum, int nb) {
  __shared__ int sm[1024];
  int t = threadIdx.x;
  int v = (t < nb) ? bsum[t] : 0;
  sm[t] = v;
  __syncthreads();
  for (int s = 1; s < 1024; s <<= 1) {
    int a = (t >= s) ? sm[t - s] : 0;
    __syncthreads();
    sm[t] += a;
    __syncthreads();
  }
  if (t < nb) bsum[t] = sm[t] - v;
}

__global__ void k_scan3(const int* __restrict__ bsum, int* __restrict__ row,
                        int* __restrict__ cursor, int N, int E) {
  int i = blockIdx.x * blockDim.x + threadIdx.x;
  if (i < N) {
    int v = cursor[i] + bsum[i >> 8];
    row[i] = v;
    cursor[i] = v;
  }
  if (i == 0) row[N] = E;
}

__global__ void k_bucket(const int* __restrict__ src, const int* __restrict__ dst,
                         int* __restrict__ cursor, int* __restrict__ srcs, int E) {
  int e = blockIdx.x * blockDim.x + threadIdx.x;
  if (e < E) {
    int pos = atomicAdd(&cursor[dst[e]], 1);
    srcs[pos] = src[e];
  }
}

// ---------------- aggregation: one wave per node ----------------
__global__ void k_gather64(const float* __restrict__ feat, const int* __restrict__ row,
                           const int* __restrict__ srcs, float* __restrict__ agg, int N) {
  int gid = blockIdx.x * blockDim.x + threadIdx.x;
  int wid = gid >> 6, lane = gid & 63;
  if (wid >= N) return;
  int beg = row[wid], end = row[wid + 1];
  float acc = 0.f;
  for (int k = beg; k < end; k++) {
    int s = srcs[k];
    acc += feat[(size_t)s * 64 + lane];
  }
  agg[(size_t)wid * 64 + lane] = acc;
}

// ---------------- tiled node GEMM: out[N][J] ----------------
// MODE 0 (h1): acc = A@W ; acc *= inv(deg) ; acc += A2@Wb ; acc += bias
// MODE 1 (g):  acc = A@W
// MODE 2 (h2): acc = A@W ; acc += add64*inv(deg) + bias
template <int K, int J, int MODE>
__global__ __launch_bounds__(256) void k_node_gemm(
    const float* __restrict__ A, const float* __restrict__ A2,
    const float* __restrict__ W, const float* __restrict__ Wb,
    const float* __restrict__ bias, const float* __restrict__ add64,
    const int* __restrict__ deg, float* __restrict__ out, int N) {
  constexpr int JT = J / 4;       // j-threads (32 or 16)
  constexpr int NT = 256 / JT;    // node-threads (8 or 16)
  constexpr int NPT = 64 / NT;    // nodes per thread (8 or 4)
  constexpr int BK = 16;
  __shared__ float At[BK][64];
  __shared__ float Wt[BK][J];

  const int t = threadIdx.x;
  const int jt = t % JT, nt = t / JT;
  const int j0 = jt * 4, n0 = nt * NPT;
  const int nbase = blockIdx.x * 64;

  float4 acc[NPT];
#pragma unroll
  for (int r = 0; r < NPT; r++) acc[r] = make_float4(0.f, 0.f, 0.f, 0.f);

  auto phase = [&](const float* __restrict__ S, const float* __restrict__ Wm) {
    for (int kb = 0; kb < K; kb += BK) {
      {  // stage A-tile transposed: At[k][node]
        int n = t >> 2, kq = t & 3;
        int node = nbase + n;
        int nclamp = node < N ? node : N - 1;
        float4 v = *(const float4*)(S + (size_t)nclamp * K + kb + kq * 4);
        At[kq * 4 + 0][n] = v.x;
        At[kq * 4 + 1][n] = v.y;
        At[kq * 4 + 2][n] = v.z;
        At[kq * 4 + 3][n] = v.w;
      }
      {  // stage W-tile: rows kb..kb+BK, linear copy
        const float* wsrc = Wm + (size_t)kb * J;
        float* wdst = &Wt[0][0];
#pragma unroll
        for (int p = 0; p < (BK * J) / (256 * 4); p++) {
          int idx = (t + p * 256) * 4;
          *(float4*)(wdst + idx) = *(const float4*)(wsrc + idx);
        }
      }
      __syncthreads();
#pragma unroll
      for (int kk = 0; kk < BK; kk++) {
        float4 w = *(const float4*)&Wt[kk][j0];
        float av[NPT];
#pragma unroll
        for (int rq = 0; rq < NPT / 4; rq++) {
          float4 a = *(const float4*)&At[kk][n0 + rq * 4];
          av[rq * 4 + 0] = a.x;
          av[rq * 4 + 1] = a.y;
          av[rq * 4 + 2] = a.z;
          av[rq * 4 + 3] = a.w;
        }
#pragma unroll
        for (int r = 0; r < NPT; r++) {
          acc[r].x += av[r] * w.x;
          acc[r].y += av[r] * w.y;
          acc[r].z += av[r] * w.z;
          acc[r].w += av[r] * w.w;
        }
      }
      __syncthreads();
    }
  };

  phase(A, W);

  if constexpr (MODE == 0) {
#pragma unroll
    for (int r = 0; r < NPT; r++) {
      int node = nbase + n0 + r;
      float inv = (node < N) ? 1.0f / fmaxf((float)deg[node], 1.0f) : 1.f;
      acc[r].x *= inv; acc[r].y *= inv; acc[r].z *= inv; acc[r].w *= inv;
    }
    phase(A2, Wb);
    float4 b = *(const float4*)&bias[j0];
#pragma unroll
    for (int r = 0; r < NPT; r++) {
      acc[r].x += b.x; acc[r].y += b.y; acc[r].z += b.z; acc[r].w += b.w;
    }
  }
  if constexpr (MODE == 2) {
    float4 b = *(const float4*)&bias[j0];
#pragma unroll
    for (int r = 0; r < NPT; r++) {
      int node = nbase + n0 + r;
      if (node < N) {
        float inv = 1.0f / fmaxf((float)deg[node], 1.0f);
        float4 ad = *(const float4*)(add64 + (size_t)node * J + j0);
        acc[r].x += ad.x * inv + b.x;
        acc[r].y += ad.y * inv + b.y;
        acc[r].z += ad.z * inv + b.z;
        acc[r].w += ad.w * inv + b.w;
      }
    }
  }

#pragma unroll
  for (int r = 0; r < NPT; r++) {
    int node = nbase + n0 + r;
    if (node < N) *(float4*)(out + (size_t)node * J + j0) = acc[r];
  }
}

// ---------------- edge MLP: one edge per lane ----------------
__global__ __launch_bounds__(256) void k_edge(
    const float* __restrict__ h2, const int* __restrict__ src,
    const int* __restrict__ dst, const float* __restrict__ W1t,
    const float* __restrict__ W2, const float* __restrict__ b1,
    const float* __restrict__ b2, float* __restrict__ out, int E) {
  int e = blockIdx.x * blockDim.x + threadIdx.x;
  if (e >= E) return;
  int s = src[e], d = dst[e];
  float ev[64];
  const float4* hs = (const float4*)(h2 + (size_t)s * 64);
  const float4* hd = (const float4*)(h2 + (size_t)d * 64);
#pragma unroll
  for (int i = 0; i < 16; i++) {
    float4 a = hs[i], b = hd[i];
    ev[4 * i] = a.x * b.x; ev[4 * i + 1] = a.y * b.y;
    ev[4 * i + 2] = a.z * b.z; ev[4 * i + 3] = a.w * b.w;
  }
  float o = b2[0];
  for (int k = 0; k < 128; k++) {
    float a0 = 0.f, a1 = 0.f, a2 = 0.f, a3 = 0.f;
#pragma unroll
    for (int i = 0; i < 64; i += 4) {
      a0 += ev[i] * W1t[k * 64 + i];
      a1 += ev[i + 1] * W1t[k * 64 + i + 1];
      a2 += ev[i + 2] * W1t[k * 64 + i + 2];
      a3 += ev[i + 3] * W1t[k * 64 + i + 3];
    }
    float tt = a0 + a1 + a2 + a3 + b1[k];
    o += fmaxf(tt, 0.f) * W2[k];
  }
  out[e] = o;
}

// ---------------- launch ----------------
extern "C" void kernel_launch(void* const* d_in, const int* in_sizes, int n_in,
                              void* d_out, int out_size, void* d_ws, size_t ws_size,
                              hipStream_t stream) {
  const float* x   = (const float*)d_in[0];
  const int*   ei  = (const int*)d_in[1];
  const float* Wl1 = (const float*)d_in[2];
  const float* bl1 = (const float*)d_in[3];
  const float* Wr1 = (const float*)d_in[4];
  const float* Wl2 = (const float*)d_in[5];
  const float* bl2 = (const float*)d_in[6];
  const float* Wr2 = (const float*)d_in[7];
  const float* W1  = (const float*)d_in[8];
  const float* b1  = (const float*)d_in[9];
  const float* W2  = (const float*)d_in[10];
  const float* b2  = (const float*)d_in[11];
  const int N = in_sizes[0] / 64;
  const int E = in_sizes[1] / 2;
  const int* src = ei;
  const int* dstp = ei + E;

  char* w = (char*)d_ws;
  size_t off = 0;
  auto alloc = [&](size_t bytes) -> void* {
    void* p = w + off;
    off = (off + bytes + 255) & ~(size_t)255;
    return p;
  };
  int*   deg    = (int*)alloc((size_t)N * 4);
  int*   row    = (int*)alloc((size_t)(N + 1) * 4);
  int*   cursor = (int*)alloc((size_t)N * 4);
  int*   bsum   = (int*)alloc(1024 * 4);
  float* W1t    = (float*)alloc(8192 * 4);
  int*   srcs   = (int*)alloc((size_t)E * 4);
  float* aggX   = (float*)alloc((size_t)N * 64 * 4);   // reused as aggG
  float* h1     = (float*)alloc((size_t)N * 128 * 4);
  float* gbuf   = (float*)alloc((size_t)N * 64 * 4);   // g, reused as h2

  hipMemsetAsync(deg, 0, (size_t)N * 4, stream);
  k_prep<<<32, 256, 0, stream>>>(W1, W1t);
  k_hist<<<(E + 255) / 256, 256, 0, stream>>>(dstp, deg, E);
  int nb = (N + 255) / 256;
  k_scan1<<<nb, 256, 0, stream>>>(deg, cursor, bsum, N);
  k_scan2<<<1, 1024, 0, stream>>>(bsum, nb);
  k_scan3<<<nb, 256, 0, stream>>>(bsum, row, cursor, N, E);
  k_bucket<<<(E + 255) / 256, 256, 0, stream>>>(src, dstp, cursor, srcs, E);

  int ngrid = (N + 63) / 64;
  k_gather64<<<(N * 64 + 255) / 256, 256, 0, stream>>>(x, row, srcs, aggX, N);
  k_node_gemm<64, 128, 0><<<ngrid, 256, 0, stream>>>(
      aggX, x, Wl1, Wr1, bl1, nullptr, deg, h1, N);
  k_node_gemm<128, 64, 1><<<ngrid, 256, 0, stream>>>(
      h1, nullptr, Wl2, nullptr, nullptr, nullptr, nullptr, gbuf, N);
  k_gather64<<<(N * 64 + 255) / 256, 256, 0, stream>>>(gbuf, row, srcs, aggX, N);
  k_node_gemm<128, 64, 2><<<ngrid, 256, 0, stream>>>(
      h1, nullptr, Wr2, nullptr, bl2, aggX, deg, gbuf, N);
  k_edge<<<(E + 255) / 256, 256, 0, stream>>>(gbuf, src, dstp, W1t, W2, b1, b2,
                                              (float*)d_out, E);
}

// Round 3
// 444.617 us; speedup vs baseline: 3.4885x; 1.6547x over previous
//
#include <hip/hip_runtime.h>

// GraphSAGE link predictor. f32 node GEMMs (LDS-tiled), f16 gathers, f16-MFMA edge MLP.
// Pipeline:
//  CSR build (deg hist -> scan -> bucket with src/dst/eid permutation)
//  x16  = f16(x)
//  aggX = segsum(x16[src])                      (gather, 16 lanes/row, f32 accum)
//  h1   = (aggX@Wl1)*inv + x@Wr1 + bl1          (tiled GEMM, MODE 0, f32 out)
//  g16  = f16(h1@Wl2)                           (tiled GEMM, MODE 1, f16 out)
//  aggG = segsum(g16[src])                      (gather)
//  h2_16= f16(h1@Wr2 + aggG*inv + bl2)          (tiled GEMM, MODE 2, f16 out)
//  out[eid] = relu((h2[s]*h2[d])@W1+b1)@W2 + b2 (MFMA f16, CSR edge order, scatter)

typedef _Float16 f16x8 __attribute__((ext_vector_type(8)));
typedef float f32x4 __attribute__((ext_vector_type(4)));

union H4 { _Float16 h[4]; uint2 u; };

// ---------------- f32 -> f16 pack (x16) ----------------
__global__ void k_f32_to_f16(const float* __restrict__ in, _Float16* __restrict__ out,
                             int n4) {
  int t = blockIdx.x * blockDim.x + threadIdx.x;
  if (t >= n4) return;
  float4 v = ((const float4*)in)[t];
  H4 p;
  p.h[0] = (_Float16)v.x; p.h[1] = (_Float16)v.y;
  p.h[2] = (_Float16)v.z; p.h[3] = (_Float16)v.w;
  ((uint2*)out)[t] = p.u;
}

// ---------------- CSR build ----------------
__global__ void k_hist(const int* __restrict__ dst, int* __restrict__ deg, int E) {
  int e = blockIdx.x * blockDim.x + threadIdx.x;
  if (e < E) atomicAdd(&deg[dst[e]], 1);
}

__global__ void k_scan1(const int* __restrict__ deg, int* __restrict__ ex,
                        int* __restrict__ bsum, int N) {
  __shared__ int sm[256];
  int t = threadIdx.x, i = blockIdx.x * 256 + t;
  int v = (i < N) ? deg[i] : 0;
  sm[t] = v;
  __syncthreads();
  for (int s = 1; s < 256; s <<= 1) {
    int a = (t >= s) ? sm[t - s] : 0;
    __syncthreads();
    sm[t] += a;
    __syncthreads();
  }
  if (i < N) ex[i] = sm[t] - v;
  if (t == 255) bsum[blockIdx.x] = sm[255];
}

__global__ void k_scan2(int* __restrict__ bsum, int nb) {
  __shared__ int sm[1024];
  int t = threadIdx.x;
  int v = (t < nb) ? bsum[t] : 0;
  sm[t] = v;
  __syncthreads();
  for (int s = 1; s < 1024; s <<= 1) {
    int a = (t >= s) ? sm[t - s] : 0;
    __syncthreads();
    sm[t] += a;
    __syncthreads();
  }
  if (t < nb) bsum[t] = sm[t] - v;
}

__global__ void k_scan3(const int* __restrict__ bsum, int* __restrict__ row,
                        int* __restrict__ cursor, int N, int E) {
  int i = blockIdx.x * blockDim.x + threadIdx.x;
  if (i < N) {
    int v = cursor[i] + bsum[i >> 8];
    row[i] = v;
    cursor[i] = v;
  }
  if (i == 0) row[N] = E;
}

__global__ void k_bucket(const int* __restrict__ src, const int* __restrict__ dst,
                         int* __restrict__ cursor, int* __restrict__ srcs,
                         int* __restrict__ dsts, int* __restrict__ eids, int E) {
  int e = blockIdx.x * blockDim.x + threadIdx.x;
  if (e < E) {
    int d = dst[e];
    int pos = atomicAdd(&cursor[d], 1);
    srcs[pos] = src[e];
    dsts[pos] = d;
    eids[pos] = e;
  }
}

// ---------------- aggregation: 16 lanes/row, 4 rows per wave ----------------
__global__ __launch_bounds__(256) void k_gather16(
    const _Float16* __restrict__ feat, const int* __restrict__ row,
    const int* __restrict__ srcs, float* __restrict__ agg, int N) {
  int tid = blockIdx.x * blockDim.x + threadIdx.x;
  int node = tid >> 4, slot = tid & 15;
  if (node >= N) return;
  int beg = row[node], end = row[node + 1];
  float4 acc = make_float4(0.f, 0.f, 0.f, 0.f);
  int k = beg;
  for (; k + 1 < end; k += 2) {
    int s0 = srcs[k], s1 = srcs[k + 1];
    uint2 p0 = *(const uint2*)(feat + (size_t)s0 * 64 + slot * 4);
    uint2 p1 = *(const uint2*)(feat + (size_t)s1 * 64 + slot * 4);
    H4 a, b; a.u = p0; b.u = p1;
    acc.x += (float)a.h[0] + (float)b.h[0];
    acc.y += (float)a.h[1] + (float)b.h[1];
    acc.z += (float)a.h[2] + (float)b.h[2];
    acc.w += (float)a.h[3] + (float)b.h[3];
  }
  if (k < end) {
    int s0 = srcs[k];
    H4 a; a.u = *(const uint2*)(feat + (size_t)s0 * 64 + slot * 4);
    acc.x += (float)a.h[0]; acc.y += (float)a.h[1];
    acc.z += (float)a.h[2]; acc.w += (float)a.h[3];
  }
  *(float4*)(agg + (size_t)node * 64 + slot * 4) = acc;
}

// ---------------- tiled node GEMM: out[N][J] ----------------
// MODE 0 (h1): acc = A@W ; acc *= inv(deg) ; acc += A2@Wb ; acc += bias   (f32 out)
// MODE 1 (g):  acc = A@W                                                  (f16 out)
// MODE 2 (h2): acc = A@W ; acc += add64*inv(deg) + bias                   (f16 out)
template <int K, int J, int MODE, int OUTF16>
__global__ __launch_bounds__(256) void k_node_gemm(
    const float* __restrict__ A, const float* __restrict__ A2,
    const float* __restrict__ W, const float* __restrict__ Wb,
    const float* __restrict__ bias, const float* __restrict__ add64,
    const int* __restrict__ deg, void* __restrict__ outp, int N) {
  constexpr int JT = J / 4;
  constexpr int NT = 256 / JT;
  constexpr int NPT = 64 / NT;
  constexpr int BK = 16;
  __shared__ float At[BK][64];
  __shared__ float Wt[BK][J];

  const int t = threadIdx.x;
  const int jt = t % JT, nt = t / JT;
  const int j0 = jt * 4, n0 = nt * NPT;
  const int nbase = blockIdx.x * 64;

  float4 acc[NPT];
#pragma unroll
  for (int r = 0; r < NPT; r++) acc[r] = make_float4(0.f, 0.f, 0.f, 0.f);

  auto phase = [&](const float* __restrict__ S, const float* __restrict__ Wm) {
    for (int kb = 0; kb < K; kb += BK) {
      {
        int n = t >> 2, kq = t & 3;
        int node = nbase + n;
        int nclamp = node < N ? node : N - 1;
        float4 v = *(const float4*)(S + (size_t)nclamp * K + kb + kq * 4);
        At[kq * 4 + 0][n] = v.x;
        At[kq * 4 + 1][n] = v.y;
        At[kq * 4 + 2][n] = v.z;
        At[kq * 4 + 3][n] = v.w;
      }
      {
        const float* wsrc = Wm + (size_t)kb * J;
        float* wdst = &Wt[0][0];
#pragma unroll
        for (int p = 0; p < (BK * J) / (256 * 4); p++) {
          int idx = (t + p * 256) * 4;
          *(float4*)(wdst + idx) = *(const float4*)(wsrc + idx);
        }
      }
      __syncthreads();
#pragma unroll
      for (int kk = 0; kk < BK; kk++) {
        float4 w = *(const float4*)&Wt[kk][j0];
        float av[NPT];
#pragma unroll
        for (int rq = 0; rq < NPT / 4; rq++) {
          float4 a = *(const float4*)&At[kk][n0 + rq * 4];
          av[rq * 4 + 0] = a.x;
          av[rq * 4 + 1] = a.y;
          av[rq * 4 + 2] = a.z;
          av[rq * 4 + 3] = a.w;
        }
#pragma unroll
        for (int r = 0; r < NPT; r++) {
          acc[r].x += av[r] * w.x;
          acc[r].y += av[r] * w.y;
          acc[r].z += av[r] * w.z;
          acc[r].w += av[r] * w.w;
        }
      }
      __syncthreads();
    }
  };

  phase(A, W);

  if constexpr (MODE == 0) {
#pragma unroll
    for (int r = 0; r < NPT; r++) {
      int node = nbase + n0 + r;
      float inv = (node < N) ? 1.0f / fmaxf((float)deg[node], 1.0f) : 1.f;
      acc[r].x *= inv; acc[r].y *= inv; acc[r].z *= inv; acc[r].w *= inv;
    }
    phase(A2, Wb);
    float4 b = *(const float4*)&bias[j0];
#pragma unroll
    for (int r = 0; r < NPT; r++) {
      acc[r].x += b.x; acc[r].y += b.y; acc[r].z += b.z; acc[r].w += b.w;
    }
  }
  if constexpr (MODE == 2) {
    float4 b = *(const float4*)&bias[j0];
#pragma unroll
    for (int r = 0; r < NPT; r++) {
      int node = nbase + n0 + r;
      if (node < N) {
        float inv = 1.0f / fmaxf((float)deg[node], 1.0f);
        float4 ad = *(const float4*)(add64 + (size_t)node * J + j0);
        acc[r].x += ad.x * inv + b.x;
        acc[r].y += ad.y * inv + b.y;
        acc[r].z += ad.z * inv + b.z;
        acc[r].w += ad.w * inv + b.w;
      }
    }
  }

#pragma unroll
  for (int r = 0; r < NPT; r++) {
    int node = nbase + n0 + r;
    if (node < N) {
      if constexpr (OUTF16) {
        H4 p;
        p.h[0] = (_Float16)acc[r].x; p.h[1] = (_Float16)acc[r].y;
        p.h[2] = (_Float16)acc[r].z; p.h[3] = (_Float16)acc[r].w;
        *(uint2*)((_Float16*)outp + (size_t)node * J + j0) = p.u;
      } else {
        *(float4*)((float*)outp + (size_t)node * J + j0) = acc[r];
      }
    }
  }
}

// ---------------- edge MLP via f16 MFMA, 16 edges per wave-group ----------------
// A = ev[16 edges x 64], B = W1[64 x 128] in 8 col-tiles x 2 k-steps.
// D[edge][hid]: col = lane&15 (hid), row = (lane>>4)*4 + reg (edge).
// A frag: lane holds A[lane&15][8*(lane>>4) + e], e=0..7 (per 32-k step).
// B frag: lane holds B[8*(lane>>4) + e][lane&15].
__global__ __launch_bounds__(256) void k_edge_mfma(
    const _Float16* __restrict__ h2, const int* __restrict__ srcs,
    const int* __restrict__ dsts, const int* __restrict__ eids,
    const float* __restrict__ W1, const float* __restrict__ W2,
    const float* __restrict__ b1, const float* __restrict__ b2,
    float* __restrict__ out, int E) {
  const int gtid = blockIdx.x * blockDim.x + threadIdx.x;
  const int wave = gtid >> 6;
  const int nwaves = (gridDim.x * blockDim.x) >> 6;
  const int l = threadIdx.x & 63;
  const int col = l & 15;
  const int kb = (l >> 4) * 8;
  const int ngroups = (E + 15) / 16;

  // preload W1 fragments (f32 -> f16), b1/W2 slices, b2
  f16x8 bfrag[8][2];
#pragma unroll
  for (int tt = 0; tt < 8; tt++)
#pragma unroll
    for (int s = 0; s < 2; s++) {
      f16x8 bf;
#pragma unroll
      for (int e = 0; e < 8; e++)
        bf[e] = (_Float16)W1[(size_t)(s * 32 + kb + e) * 128 + tt * 16 + col];
      bfrag[tt][s] = bf;
    }
  float b1r[8], w2r[8];
#pragma unroll
  for (int tt = 0; tt < 8; tt++) {
    b1r[tt] = b1[tt * 16 + col];
    w2r[tt] = W2[tt * 16 + col];
  }
  const float b2v = b2[0];

  for (int g = wave; g < ngroups; g += nwaves) {
    int pos = g * 16 + col;
    if (pos >= E) pos = E - 1;
    int sp = srcs[pos], dp = dsts[pos];
    f16x8 as0 = *(const f16x8*)(h2 + (size_t)sp * 64 + kb);
    f16x8 ad0 = *(const f16x8*)(h2 + (size_t)dp * 64 + kb);
    f16x8 as1 = *(const f16x8*)(h2 + (size_t)sp * 64 + 32 + kb);
    f16x8 ad1 = *(const f16x8*)(h2 + (size_t)dp * 64 + 32 + kb);
    f16x8 a0 = as0 * ad0;
    f16x8 a1 = as1 * ad1;

    float partial0 = 0.f, partial1 = 0.f, partial2 = 0.f, partial3 = 0.f;
#pragma unroll
    for (int tt = 0; tt < 8; tt++) {
      f32x4 acc = {0.f, 0.f, 0.f, 0.f};
      acc = __builtin_amdgcn_mfma_f32_16x16x32_f16(a0, bfrag[tt][0], acc, 0, 0, 0);
      acc = __builtin_amdgcn_mfma_f32_16x16x32_f16(a1, bfrag[tt][1], acc, 0, 0, 0);
      partial0 += fmaxf(acc[0] + b1r[tt], 0.f) * w2r[tt];
      partial1 += fmaxf(acc[1] + b1r[tt], 0.f) * w2r[tt];
      partial2 += fmaxf(acc[2] + b1r[tt], 0.f) * w2r[tt];
      partial3 += fmaxf(acc[3] + b1r[tt], 0.f) * w2r[tt];
    }
#pragma unroll
    for (int m = 1; m < 16; m <<= 1) {
      partial0 += __shfl_xor(partial0, m, 64);
      partial1 += __shfl_xor(partial1, m, 64);
      partial2 += __shfl_xor(partial2, m, 64);
      partial3 += __shfl_xor(partial3, m, 64);
    }
    if (col == 0) {
      int ebase = g * 16 + (l >> 4) * 4;
      float pv[4] = {partial0, partial1, partial2, partial3};
#pragma unroll
      for (int r = 0; r < 4; r++) {
        int ep = ebase + r;
        if (ep < E) out[eids[ep]] = pv[r] + b2v;
      }
    }
  }
}

// ---------------- launch ----------------
extern "C" void kernel_launch(void* const* d_in, const int* in_sizes, int n_in,
                              void* d_out, int out_size, void* d_ws, size_t ws_size,
                              hipStream_t stream) {
  const float* x   = (const float*)d_in[0];
  const int*   ei  = (const int*)d_in[1];
  const float* Wl1 = (const float*)d_in[2];
  const float* bl1 = (const float*)d_in[3];
  const float* Wr1 = (const float*)d_in[4];
  const float* Wl2 = (const float*)d_in[5];
  const float* bl2 = (const float*)d_in[6];
  const float* Wr2 = (const float*)d_in[7];
  const float* W1  = (const float*)d_in[8];
  const float* b1  = (const float*)d_in[9];
  const float* W2  = (const float*)d_in[10];
  const float* b2  = (const float*)d_in[11];
  const int N = in_sizes[0] / 64;
  const int E = in_sizes[1] / 2;
  const int* src = ei;
  const int* dstp = ei + E;

  char* w = (char*)d_ws;
  size_t off = 0;
  auto alloc = [&](size_t bytes) -> void* {
    void* p = w + off;
    off = (off + bytes + 255) & ~(size_t)255;
    return p;
  };
  int*      deg    = (int*)alloc((size_t)N * 4);
  int*      row    = (int*)alloc((size_t)(N + 1) * 4);
  int*      cursor = (int*)alloc((size_t)N * 4);
  int*      bsum   = (int*)alloc(1024 * 4);
  int*      srcs   = (int*)alloc((size_t)E * 4);
  int*      dsts   = (int*)alloc((size_t)E * 4);
  int*      eids   = (int*)alloc((size_t)E * 4);
  _Float16* f16buf = (_Float16*)alloc((size_t)N * 64 * 2);  // x16 -> g16 -> h2_16
  float*    aggX   = (float*)alloc((size_t)N * 64 * 4);     // reused as aggG
  float*    h1     = (float*)alloc((size_t)N * 128 * 4);

  hipMemsetAsync(deg, 0, (size_t)N * 4, stream);
  k_f32_to_f16<<<(N * 16 + 255) / 256, 256, 0, stream>>>(x, f16buf, N * 16);
  k_hist<<<(E + 255) / 256, 256, 0, stream>>>(dstp, deg, E);
  int nb = (N + 255) / 256;
  k_scan1<<<nb, 256, 0, stream>>>(deg, cursor, bsum, N);
  k_scan2<<<1, 1024, 0, stream>>>(bsum, nb);
  k_scan3<<<nb, 256, 0, stream>>>(bsum, row, cursor, N, E);
  k_bucket<<<(E + 255) / 256, 256, 0, stream>>>(src, dstp, cursor, srcs, dsts, eids, E);

  int ngrid = (N + 63) / 64;
  int ggrid = (N * 16 + 255) / 256;
  k_gather16<<<ggrid, 256, 0, stream>>>(f16buf, row, srcs, aggX, N);
  k_node_gemm<64, 128, 0, 0><<<ngrid, 256, 0, stream>>>(
      aggX, x, Wl1, Wr1, bl1, nullptr, deg, h1, N);
  k_node_gemm<128, 64, 1, 1><<<ngrid, 256, 0, stream>>>(
      h1, nullptr, Wl2, nullptr, nullptr, nullptr, nullptr, f16buf, N);
  k_gather16<<<ggrid, 256, 0, stream>>>(f16buf, row, srcs, aggX, N);
  k_node_gemm<128, 64, 2, 1><<<ngrid, 256, 0, stream>>>(
      h1, nullptr, Wr2, nullptr, bl2, aggX, deg, f16buf, N);
  k_edge_mfma<<<1024, 256, 0, stream>>>(f16buf, srcs, dsts, eids, W1, W2, b1, b2,
                                        (float*)d_out, E);
}

// Round 4
// 406.136 us; speedup vs baseline: 3.8190x; 1.0947x over previous
//
#include <hip/hip_runtime.h>

// GraphSAGE link predictor. f32 node GEMMs (LDS-tiled), f16 gathers, f16-MFMA edge MLP.
// Pipeline:
//  CSR build (deg hist -> scan -> bucket, srcs only)
//  x16  = f16(x)
//  aggX = segsum(x16[src])                      (gather, 16 lanes/row, f32 accum)
//  h1   = (aggX@Wl1)*inv + x@Wr1 + bl1          (tiled GEMM, MODE 0, f32 out)
//  g16  = f16(h1@Wl2)                           (tiled GEMM, MODE 1, f16 out)
//  aggG = segsum(g16[src])                      (gather)
//  h2_16= f16(h1@Wr2 + aggG*inv + bl2)          (tiled GEMM, MODE 2, f16 out)
//  out[e] = relu((h2[s]*h2[d])@W1+b1)@W2 + b2   (MFMA f16, ORIGINAL edge order,
//                                                coalesced writes, dbuf group pipeline)

typedef _Float16 f16x8 __attribute__((ext_vector_type(8)));
typedef float f32x4 __attribute__((ext_vector_type(4)));

union H4 { _Float16 h[4]; uint2 u; };

// ---------------- f32 -> f16 pack ----------------
__global__ void k_f32_to_f16(const float* __restrict__ in, _Float16* __restrict__ out,
                             int n4) {
  int t = blockIdx.x * blockDim.x + threadIdx.x;
  if (t >= n4) return;
  float4 v = ((const float4*)in)[t];
  H4 p;
  p.h[0] = (_Float16)v.x; p.h[1] = (_Float16)v.y;
  p.h[2] = (_Float16)v.z; p.h[3] = (_Float16)v.w;
  ((uint2*)out)[t] = p.u;
}

// ---------------- CSR build ----------------
__global__ void k_hist(const int* __restrict__ dst, int* __restrict__ deg, int E) {
  int e = blockIdx.x * blockDim.x + threadIdx.x;
  if (e < E) atomicAdd(&deg[dst[e]], 1);
}

__global__ void k_scan1(const int* __restrict__ deg, int* __restrict__ ex,
                        int* __restrict__ bsum, int N) {
  __shared__ int sm[256];
  int t = threadIdx.x, i = blockIdx.x * 256 + t;
  int v = (i < N) ? deg[i] : 0;
  sm[t] = v;
  __syncthreads();
  for (int s = 1; s < 256; s <<= 1) {
    int a = (t >= s) ? sm[t - s] : 0;
    __syncthreads();
    sm[t] += a;
    __syncthreads();
  }
  if (i < N) ex[i] = sm[t] - v;
  if (t == 255) bsum[blockIdx.x] = sm[255];
}

__global__ void k_scan2(int* __restrict__ bsum, int nb) {
  __shared__ int sm[1024];
  int t = threadIdx.x;
  int v = (t < nb) ? bsum[t] : 0;
  sm[t] = v;
  __syncthreads();
  for (int s = 1; s < 1024; s <<= 1) {
    int a = (t >= s) ? sm[t - s] : 0;
    __syncthreads();
    sm[t] += a;
    __syncthreads();
  }
  if (t < nb) bsum[t] = sm[t] - v;
}

__global__ void k_scan3(const int* __restrict__ bsum, int* __restrict__ row,
                        int* __restrict__ cursor, int N, int E) {
  int i = blockIdx.x * blockDim.x + threadIdx.x;
  if (i < N) {
    int v = cursor[i] + bsum[i >> 8];
    row[i] = v;
    cursor[i] = v;
  }
  if (i == 0) row[N] = E;
}

__global__ void k_bucket(const int* __restrict__ src, const int* __restrict__ dst,
                         int* __restrict__ cursor, int* __restrict__ srcs, int E) {
  int e = blockIdx.x * blockDim.x + threadIdx.x;
  if (e < E) {
    int pos = atomicAdd(&cursor[dst[e]], 1);
    srcs[pos] = src[e];
  }
}

// ---------------- aggregation: 16 lanes/row, unroll 4 ----------------
__global__ __launch_bounds__(256) void k_gather16(
    const _Float16* __restrict__ feat, const int* __restrict__ row,
    const int* __restrict__ srcs, float* __restrict__ agg, int N) {
  int tid = blockIdx.x * blockDim.x + threadIdx.x;
  int node = tid >> 4, slot = tid & 15;
  if (node >= N) return;
  int beg = row[node], end = row[node + 1];
  float4 acc = make_float4(0.f, 0.f, 0.f, 0.f);
  int k = beg;
  for (; k + 3 < end; k += 4) {
    int s0 = srcs[k], s1 = srcs[k + 1], s2 = srcs[k + 2], s3 = srcs[k + 3];
    H4 a, b, c, d;
    a.u = *(const uint2*)(feat + (size_t)s0 * 64 + slot * 4);
    b.u = *(const uint2*)(feat + (size_t)s1 * 64 + slot * 4);
    c.u = *(const uint2*)(feat + (size_t)s2 * 64 + slot * 4);
    d.u = *(const uint2*)(feat + (size_t)s3 * 64 + slot * 4);
    acc.x += ((float)a.h[0] + (float)b.h[0]) + ((float)c.h[0] + (float)d.h[0]);
    acc.y += ((float)a.h[1] + (float)b.h[1]) + ((float)c.h[1] + (float)d.h[1]);
    acc.z += ((float)a.h[2] + (float)b.h[2]) + ((float)c.h[2] + (float)d.h[2]);
    acc.w += ((float)a.h[3] + (float)b.h[3]) + ((float)c.h[3] + (float)d.h[3]);
  }
  for (; k < end; k++) {
    int s0 = srcs[k];
    H4 a; a.u = *(const uint2*)(feat + (size_t)s0 * 64 + slot * 4);
    acc.x += (float)a.h[0]; acc.y += (float)a.h[1];
    acc.z += (float)a.h[2]; acc.w += (float)a.h[3];
  }
  *(float4*)(agg + (size_t)node * 64 + slot * 4) = acc;
}

// ---------------- tiled node GEMM: out[N][J] ----------------
template <int K, int J, int MODE, int OUTF16>
__global__ __launch_bounds__(256) void k_node_gemm(
    const float* __restrict__ A, const float* __restrict__ A2,
    const float* __restrict__ W, const float* __restrict__ Wb,
    const float* __restrict__ bias, const float* __restrict__ add64,
    const int* __restrict__ deg, void* __restrict__ outp, int N) {
  constexpr int JT = J / 4;
  constexpr int NT = 256 / JT;
  constexpr int NPT = 64 / NT;
  constexpr int BK = 16;
  __shared__ float At[BK][64];
  __shared__ float Wt[BK][J];

  const int t = threadIdx.x;
  const int jt = t % JT, nt = t / JT;
  const int j0 = jt * 4, n0 = nt * NPT;
  const int nbase = blockIdx.x * 64;

  float4 acc[NPT];
#pragma unroll
  for (int r = 0; r < NPT; r++) acc[r] = make_float4(0.f, 0.f, 0.f, 0.f);

  auto phase = [&](const float* __restrict__ S, const float* __restrict__ Wm) {
    for (int kb = 0; kb < K; kb += BK) {
      {
        int n = t >> 2, kq = t & 3;
        int node = nbase + n;
        int nclamp = node < N ? node : N - 1;
        float4 v = *(const float4*)(S + (size_t)nclamp * K + kb + kq * 4);
        At[kq * 4 + 0][n] = v.x;
        At[kq * 4 + 1][n] = v.y;
        At[kq * 4 + 2][n] = v.z;
        At[kq * 4 + 3][n] = v.w;
      }
      {
        const float* wsrc = Wm + (size_t)kb * J;
        float* wdst = &Wt[0][0];
#pragma unroll
        for (int p = 0; p < (BK * J) / (256 * 4); p++) {
          int idx = (t + p * 256) * 4;
          *(float4*)(wdst + idx) = *(const float4*)(wsrc + idx);
        }
      }
      __syncthreads();
#pragma unroll
      for (int kk = 0; kk < BK; kk++) {
        float4 w = *(const float4*)&Wt[kk][j0];
        float av[NPT];
#pragma unroll
        for (int rq = 0; rq < NPT / 4; rq++) {
          float4 a = *(const float4*)&At[kk][n0 + rq * 4];
          av[rq * 4 + 0] = a.x;
          av[rq * 4 + 1] = a.y;
          av[rq * 4 + 2] = a.z;
          av[rq * 4 + 3] = a.w;
        }
#pragma unroll
        for (int r = 0; r < NPT; r++) {
          acc[r].x += av[r] * w.x;
          acc[r].y += av[r] * w.y;
          acc[r].z += av[r] * w.z;
          acc[r].w += av[r] * w.w;
        }
      }
      __syncthreads();
    }
  };

  phase(A, W);

  if constexpr (MODE == 0) {
#pragma unroll
    for (int r = 0; r < NPT; r++) {
      int node = nbase + n0 + r;
      float inv = (node < N) ? 1.0f / fmaxf((float)deg[node], 1.0f) : 1.f;
      acc[r].x *= inv; acc[r].y *= inv; acc[r].z *= inv; acc[r].w *= inv;
    }
    phase(A2, Wb);
    float4 b = *(const float4*)&bias[j0];
#pragma unroll
    for (int r = 0; r < NPT; r++) {
      acc[r].x += b.x; acc[r].y += b.y; acc[r].z += b.z; acc[r].w += b.w;
    }
  }
  if constexpr (MODE == 2) {
    float4 b = *(const float4*)&bias[j0];
#pragma unroll
    for (int r = 0; r < NPT; r++) {
      int node = nbase + n0 + r;
      if (node < N) {
        float inv = 1.0f / fmaxf((float)deg[node], 1.0f);
        float4 ad = *(const float4*)(add64 + (size_t)node * J + j0);
        acc[r].x += ad.x * inv + b.x;
        acc[r].y += ad.y * inv + b.y;
        acc[r].z += ad.z * inv + b.z;
        acc[r].w += ad.w * inv + b.w;
      }
    }
  }

#pragma unroll
  for (int r = 0; r < NPT; r++) {
    int node = nbase + n0 + r;
    if (node < N) {
      if constexpr (OUTF16) {
        H4 p;
        p.h[0] = (_Float16)acc[r].x; p.h[1] = (_Float16)acc[r].y;
        p.h[2] = (_Float16)acc[r].z; p.h[3] = (_Float16)acc[r].w;
        *(uint2*)((_Float16*)outp + (size_t)node * J + j0) = p.u;
      } else {
        *(float4*)((float*)outp + (size_t)node * J + j0) = acc[r];
      }
    }
  }
}

// ---------------- edge MLP via f16 MFMA, original edge order ----------------
// A = ev[16 edges x 64], B = W1[64 x 128] in 8 col-tiles x 2 k-steps.
// D[edge][hid]: col = lane&15 (hid), row = (lane>>4)*4 + reg (edge).
__global__ __launch_bounds__(256) void k_edge_mfma(
    const _Float16* __restrict__ h2, const int* __restrict__ src,
    const int* __restrict__ dst,
    const float* __restrict__ W1, const float* __restrict__ W2,
    const float* __restrict__ b1, const float* __restrict__ b2,
    float* __restrict__ out, int E) {
  const int gtid = blockIdx.x * blockDim.x + threadIdx.x;
  const int wave = gtid >> 6;
  const int nwaves = (gridDim.x * blockDim.x) >> 6;
  const int l = threadIdx.x & 63;
  const int col = l & 15;
  const int kb = (l >> 4) * 8;
  const int ngroups = (E + 15) / 16;
  const int gpw = (ngroups + nwaves - 1) / nwaves;
  const int g0 = wave * gpw;
  const int g1 = min(g0 + gpw, ngroups);
  if (g0 >= ngroups) return;

  // preload W1 fragments (f32 -> f16), b1/W2 slices, b2
  f16x8 bfrag[8][2];
#pragma unroll
  for (int tt = 0; tt < 8; tt++)
#pragma unroll
    for (int s = 0; s < 2; s++) {
      f16x8 bf;
#pragma unroll
      for (int e = 0; e < 8; e++)
        bf[e] = (_Float16)W1[(size_t)(s * 32 + kb + e) * 128 + tt * 16 + col];
      bfrag[tt][s] = bf;
    }
  float b1r[8], w2r[8];
#pragma unroll
  for (int tt = 0; tt < 8; tt++) {
    b1r[tt] = b1[tt * 16 + col];
    w2r[tt] = W2[tt * 16 + col];
  }
  const float b2v = b2[0];

  auto ldrows = [&](int g, f16x8& a0, f16x8& a1) {
    int pos = g * 16 + col;
    if (pos >= E) pos = E - 1;
    int sp = src[pos], dp = dst[pos];
    f16x8 as0 = *(const f16x8*)(h2 + (size_t)sp * 64 + kb);
    f16x8 ad0 = *(const f16x8*)(h2 + (size_t)dp * 64 + kb);
    f16x8 as1 = *(const f16x8*)(h2 + (size_t)sp * 64 + 32 + kb);
    f16x8 ad1 = *(const f16x8*)(h2 + (size_t)dp * 64 + 32 + kb);
    a0 = as0 * ad0;
    a1 = as1 * ad1;
  };

  auto compute = [&](int g, f16x8 a0, f16x8 a1) {
    float p0 = 0.f, p1 = 0.f, p2 = 0.f, p3 = 0.f;
#pragma unroll
    for (int tt = 0; tt < 8; tt++) {
      f32x4 acc = {0.f, 0.f, 0.f, 0.f};
      acc = __builtin_amdgcn_mfma_f32_16x16x32_f16(a0, bfrag[tt][0], acc, 0, 0, 0);
      acc = __builtin_amdgcn_mfma_f32_16x16x32_f16(a1, bfrag[tt][1], acc, 0, 0, 0);
      p0 += fmaxf(acc[0] + b1r[tt], 0.f) * w2r[tt];
      p1 += fmaxf(acc[1] + b1r[tt], 0.f) * w2r[tt];
      p2 += fmaxf(acc[2] + b1r[tt], 0.f) * w2r[tt];
      p3 += fmaxf(acc[3] + b1r[tt], 0.f) * w2r[tt];
    }
#pragma unroll
    for (int m = 1; m < 16; m <<= 1) {
      p0 += __shfl_xor(p0, m, 64);
      p1 += __shfl_xor(p1, m, 64);
      p2 += __shfl_xor(p2, m, 64);
      p3 += __shfl_xor(p3, m, 64);
    }
    if (col == 0) {
      int ebase = g * 16 + (l >> 4) * 4;
      float pv[4] = {p0, p1, p2, p3};
#pragma unroll
      for (int r = 0; r < 4; r++) {
        int ep = ebase + r;
        if (ep < E) out[ep] = pv[r] + b2v;
      }
    }
  };

  f16x8 a0, a1, na0, na1;
  ldrows(g0, a0, a1);
  for (int g = g0; g < g1; g++) {
    if (g + 1 < g1) ldrows(g + 1, na0, na1);
    compute(g, a0, a1);
    a0 = na0; a1 = na1;
  }
}

// ---------------- launch ----------------
extern "C" void kernel_launch(void* const* d_in, const int* in_sizes, int n_in,
                              void* d_out, int out_size, void* d_ws, size_t ws_size,
                              hipStream_t stream) {
  const float* x   = (const float*)d_in[0];
  const int*   ei  = (const int*)d_in[1];
  const float* Wl1 = (const float*)d_in[2];
  const float* bl1 = (const float*)d_in[3];
  const float* Wr1 = (const float*)d_in[4];
  const float* Wl2 = (const float*)d_in[5];
  const float* bl2 = (const float*)d_in[6];
  const float* Wr2 = (const float*)d_in[7];
  const float* W1  = (const float*)d_in[8];
  const float* b1  = (const float*)d_in[9];
  const float* W2  = (const float*)d_in[10];
  const float* b2  = (const float*)d_in[11];
  const int N = in_sizes[0] / 64;
  const int E = in_sizes[1] / 2;
  const int* src = ei;
  const int* dstp = ei + E;

  char* w = (char*)d_ws;
  size_t off = 0;
  auto alloc = [&](size_t bytes) -> void* {
    void* p = w + off;
    off = (off + bytes + 255) & ~(size_t)255;
    return p;
  };
  int*      deg    = (int*)alloc((size_t)N * 4);
  int*      row    = (int*)alloc((size_t)(N + 1) * 4);
  int*      cursor = (int*)alloc((size_t)N * 4);
  int*      bsum   = (int*)alloc(1024 * 4);
  int*      srcs   = (int*)alloc((size_t)E * 4);
  _Float16* f16buf = (_Float16*)alloc((size_t)N * 64 * 2);  // x16 -> g16 -> h2_16
  float*    aggX   = (float*)alloc((size_t)N * 64 * 4);     // reused as aggG
  float*    h1     = (float*)alloc((size_t)N * 128 * 4);

  hipMemsetAsync(deg, 0, (size_t)N * 4, stream);
  k_f32_to_f16<<<(N * 16 + 255) / 256, 256, 0, stream>>>(x, f16buf, N * 16);
  k_hist<<<(E + 255) / 256, 256, 0, stream>>>(dstp, deg, E);
  int nb = (N + 255) / 256;
  k_scan1<<<nb, 256, 0, stream>>>(deg, cursor, bsum, N);
  k_scan2<<<1, 1024, 0, stream>>>(bsum, nb);
  k_scan3<<<nb, 256, 0, stream>>>(bsum, row, cursor, N, E);
  k_bucket<<<(E + 255) / 256, 256, 0, stream>>>(src, dstp, cursor, srcs, E);

  int ngrid = (N + 63) / 64;
  int ggrid = (N * 16 + 255) / 256;
  k_gather16<<<ggrid, 256, 0, stream>>>(f16buf, row, srcs, aggX, N);
  k_node_gemm<64, 128, 0, 0><<<ngrid, 256, 0, stream>>>(
      aggX, x, Wl1, Wr1, bl1, nullptr, deg, h1, N);
  k_node_gemm<128, 64, 1, 1><<<ngrid, 256, 0, stream>>>(
      h1, nullptr, Wl2, nullptr, nullptr, nullptr, nullptr, f16buf, N);
  k_gather16<<<ggrid, 256, 0, stream>>>(f16buf, row, srcs, aggX, N);
  k_node_gemm<128, 64, 2, 1><<<ngrid, 256, 0, stream>>>(
      h1, nullptr, Wr2, nullptr, bl2, aggX, deg, f16buf, N);
  k_edge_mfma<<<4096, 256, 0, stream>>>(f16buf, src, dstp, W1, W2, b1, b2,
                                        (float*)d_out, E);
}